// Round 1
// baseline (100.240 us; speedup 1.0000x reference)
//
#include <hip/hip_runtime.h>
#include <hip/hip_bf16.h>

#define N_IMG 2048
#define K_TXT 128
#define D_IN  768
#define H_DIM 512
#define M_TOT (N_IMG + K_TXT)   // 2176 virtual rows (img ++ txt)
#define NK    (N_IMG * K_TXT)   // 262144 outputs
#define NTILE 16                // proj n-tiles (32 cols each)
#define NSLAB 4                 // sim h-slabs
#define HS    (H_DIM / NSLAB)   // 128 h per slab

typedef __bf16 bf16x8 __attribute__((ext_vector_type(8)));
typedef float  f32x4  __attribute__((ext_vector_type(4)));
typedef float  f32x2  __attribute__((ext_vector_type(2)));

// ---------------------------------------------------------------------------
// Kernel 1: P[r][h] = X[r] @ W1half (+ b1 for txt rows), bf16 MFMA, fp32 out.
// UNCHANGED from the verified 100.1 µs version.
// ---------------------------------------------------------------------------
__global__ __launch_bounds__(256) void proj_kernel(
    const float* __restrict__ img, const float* __restrict__ txt,
    const float* __restrict__ W1, const float* __restrict__ b1,
    const float* __restrict__ W2, float* __restrict__ P,
    float* __restrict__ pw2)
{
    __shared__ __align__(16) __bf16 As[32][72];
    __shared__ __align__(16) __bf16 Bs[32][72];
    __shared__ float lds_pw[32];

    const int tid = threadIdx.x;
    const int n0 = (blockIdx.x & (NTILE - 1)) * 32;  // 16 n-tiles
    const int m0 = (blockIdx.x >> 4) * 32;           // 68 m-tiles
    const bool is_txt = (m0 >= N_IMG);
    const float* X  = is_txt ? (txt + (size_t)(m0 - N_IMG) * D_IN)
                             : (img + (size_t)m0 * D_IN);
    const float* Wb = W1 + (is_txt ? (size_t)D_IN * H_DIM : 0);

    const int wave = tid >> 6, lane = tid & 63;
    const int wm = (wave >> 1) * 16, wn = (wave & 1) * 16;
    const int quad = lane >> 4, lm = lane & 15;

    const int ar = tid >> 3, ak = (tid & 7) * 8;   // A: row ar, 8 floats at ak
    const int bn = tid & 31, bk = (tid >> 5) * 8;  // B: col bn, 8 k at bk

    f32x4 acc = {0.f, 0.f, 0.f, 0.f};
    f32x4 aR0, aR1;
    float bR[8];

    auto loadA = [&](int kc) {
        const float* ap = X + (size_t)ar * D_IN + kc + ak;
        aR0 = *(const f32x4*)(ap + 0);
        aR1 = *(const f32x4*)(ap + 4);
    };
    auto loadB = [&](int kc) {
        #pragma unroll
        for (int j = 0; j < 8; ++j)
            bR[j] = Wb[(size_t)(kc + bk + j) * H_DIM + n0 + bn];
    };

    union BPack { __bf16 h[8]; uint4 u; };

    loadA(0); loadB(0);

    for (int it = 0; it < 12; ++it) {
        BPack pa;
        #pragma unroll
        for (int j = 0; j < 4; ++j) { pa.h[j] = (__bf16)aR0[j]; pa.h[4+j] = (__bf16)aR1[j]; }
        *(uint4*)&As[ar][ak] = pa.u;
        BPack q;
        #pragma unroll
        for (int j = 0; j < 8; ++j) q.h[j] = (__bf16)bR[j];
        *(uint4*)&Bs[bn][bk] = q.u;
        __syncthreads();

        if (it < 11) { loadA((it + 1) * 64); loadB((it + 1) * 64); }

        #pragma unroll
        for (int sub = 0; sub < 2; ++sub) {
            bf16x8 af = *(bf16x8*)&As[wm + lm][sub * 32 + quad * 8];
            bf16x8 bf = *(bf16x8*)&Bs[wn + lm][sub * 32 + quad * 8];
            acc = __builtin_amdgcn_mfma_f32_16x16x32_bf16(af, bf, acc, 0, 0, 0);
        }
        __syncthreads();
    }

    // epilogue: C/D layout col=lane&15, row=quad*4+r [m89-verified];
    // write P and accumulate pw-row partials (0.5 * P . W2 over tile cols)
    float rv[4];
    {
        const int gn = n0 + wn + lm;
        const float badd = is_txt ? b1[gn] : 0.0f;
        const float w2h = 0.5f * W2[gn];
        #pragma unroll
        for (int r = 0; r < 4; ++r) {
            const int gm = m0 + wm + quad * 4 + r;
            const float v = acc[r] + badd;
            P[(size_t)gm * H_DIM + gn] = v;
            rv[r] = v * w2h;
        }
    }
    #pragma unroll
    for (int m = 1; m < 16; m <<= 1) {
        #pragma unroll
        for (int r = 0; r < 4; ++r) rv[r] += __shfl_xor(rv[r], m, 64);
    }
    // combine the 2 wn-halves per row across waves via LDS
    if (tid < 32) lds_pw[tid] = 0.f;
    __syncthreads();
    if (lm == 0) {
        #pragma unroll
        for (int r = 0; r < 4; ++r)
            atomicAdd(&lds_pw[wm + quad * 4 + r], rv[r]);
    }
    __syncthreads();
    if (tid < 32)
        pw2[(size_t)(blockIdx.x & (NTILE - 1)) * M_TOT + m0 + tid] = lds_pw[tid];
}

// ---------------------------------------------------------------------------
// Kernel 2 (v2): P2[hs][n][k] = sum_{h in 128-slab} |P_img[n,h] + P_txt[k,h]|
//                               * 0.5*W2[h]
// Tile 64n x 32k x 128h; grid 32x4x4 = 512 blocks (2/CU). Thread = 4n x 2k.
// Per wave-iter: 2 ds_read_b128 (txt) + broadcast global a/w loads vs 128
// VALU -> VALU-bound (old version was LDS-pipe-bound at 5 b128 / 64 VALU).
// Bs XOR-swizzle in 16B units: read rows tx*2+j all start at the same
// column; unswizzled their bank-quad collides 16-way. c4 ^= (row>>1)&7
// spreads the 16 tx-lanes over 8 bank-quads = 2-way = free (m136).
// ---------------------------------------------------------------------------
__global__ __launch_bounds__(256) void sim_kernel(
    const float* __restrict__ P, const float* __restrict__ W2,
    float* __restrict__ P2)
{
    __shared__ __align__(16) float Bs[32][HS];   // 16 KB txt slab, swizzled

    const int tid = threadIdx.x;
    const int n0 = blockIdx.x * 64;
    const int k0 = blockIdx.y * 32;
    const int hs = blockIdx.z;
    const int hc = hs * HS;

    // stage txt rows [k0, k0+32) x [hc, hc+128): 1024 f32x4 chunks
    #pragma unroll
    for (int i = 0; i < 4; ++i) {
        const int flat = tid + i * 256;
        const int row = flat >> 5, c4 = flat & 31;
        f32x4 v = *(const f32x4*)(P + (size_t)(N_IMG + k0 + row) * H_DIM + hc + c4 * 4);
        const int sc4 = c4 ^ ((row >> 1) & 7);
        *(f32x4*)&Bs[row][sc4 * 4] = v;
    }
    __syncthreads();

    const int tx = tid & 15;       // k-pair: rows tx*2, tx*2+1
    const int ty = tid >> 4;       // n-quad: rows n0 + ty*4 .. +3
    const int bswz = tx & 7;       // == ((tx*2+j)>>1)&7 for j in {0,1}
    const int r0 = tx * 2;
    const float* pA = P + (size_t)(n0 + ty * 4) * H_DIM + hc;

    f32x2 acc[4];
    #pragma unroll
    for (int nn = 0; nn < 4; ++nn) acc[nn] = f32x2{0.f, 0.f};

    #pragma unroll 4
    for (int h4 = 0; h4 < HS / 4; ++h4) {
        const int sc = (h4 ^ bswz) * 4;
        f32x4 w  = *(const f32x4*)(W2 + hc + h4 * 4);        // L1 broadcast
        f32x4 b0 = *(f32x4*)&Bs[r0][sc];
        f32x4 b1 = *(f32x4*)&Bs[r0 + 1][sc];
        f32x4 a[4];
        #pragma unroll
        for (int nn = 0; nn < 4; ++nn)
            a[nn] = *(const f32x4*)(pA + (size_t)nn * H_DIM + h4 * 4);  // L1 broadcast

        #pragma unroll
        for (int nn = 0; nn < 4; ++nn) {
            #pragma unroll
            for (int hh = 0; hh < 4; ++hh) {
                const float t0 = a[nn][hh] + b0[hh];
                acc[nn][0] = fmaf(fabsf(t0), w[hh], acc[nn][0]);
                const float t1 = a[nn][hh] + b1[hh];
                acc[nn][1] = fmaf(fabsf(t1), w[hh], acc[nn][1]);
            }
        }
    }

    float* o = P2 + (size_t)hs * NK + (size_t)(n0 + ty * 4) * K_TXT + k0 + tx * 2;
    #pragma unroll
    for (int nn = 0; nn < 4; ++nn) {
        f32x2 st = { acc[nn][0] * 0.5f, acc[nn][1] * 0.5f };
        *(f32x2*)(o + (size_t)nn * K_TXT) = st;
    }
}

// ---------------------------------------------------------------------------
// Kernel 3 (v2): out[n,k] = pn[n] + pk[k] + b2 + sum_{hs<4} P2[hs][n][k]
// Block = 8n x 128k (256 blocks). pw2 slice-reduction done ONCE per block
// cooperatively into LDS (136 rows of 16 slice loads) instead of 32 loads
// per thread; main loop = 4 f32x4 loads + 1 store per thread.
// ---------------------------------------------------------------------------
__global__ __launch_bounds__(256) void reduce_kernel(
    const float* __restrict__ P2, const float* __restrict__ pw2,
    const float* __restrict__ b2, float* __restrict__ out)
{
    __shared__ float pn_l[8];
    __shared__ __align__(16) float pk_l[K_TXT];

    const int tid = threadIdx.x;
    const int n0 = blockIdx.x * 8;

    if (tid < 8) {
        float s = 0.f;
        #pragma unroll
        for (int sl = 0; sl < NTILE; ++sl)
            s += pw2[(size_t)sl * M_TOT + n0 + tid];
        pn_l[tid] = s;
    } else if (tid >= 128) {
        const int k = tid - 128;
        float s = 0.f;
        #pragma unroll
        for (int sl = 0; sl < NTILE; ++sl)
            s += pw2[(size_t)sl * M_TOT + N_IMG + k];
        pk_l[k] = s;
    }
    __syncthreads();

    const int kq = tid & 31, nr = tid >> 5;
    const size_t base = (size_t)(n0 + nr) * K_TXT + kq * 4;

    f32x4 s = {0.f, 0.f, 0.f, 0.f};
    #pragma unroll
    for (int sl = 0; sl < NSLAB; ++sl)
        s += *(const f32x4*)(P2 + (size_t)sl * NK + base);

    const float add = pn_l[nr] + b2[0];
    f32x4 pk4 = *(f32x4*)&pk_l[kq * 4];
    s[0] += add + pk4[0]; s[1] += add + pk4[1];
    s[2] += add + pk4[2]; s[3] += add + pk4[3];
    *(f32x4*)(out + base) = s;
}

// ---------------------------------------------------------------------------
extern "C" void kernel_launch(void* const* d_in, const int* in_sizes, int n_in,
                              void* d_out, int out_size, void* d_ws, size_t ws_size,
                              hipStream_t stream) {
    const float* img = (const float*)d_in[0];
    const float* txt = (const float*)d_in[1];
    const float* W1  = (const float*)d_in[2];
    const float* b1  = (const float*)d_in[3];
    const float* W2  = (const float*)d_in[4];
    const float* b2  = (const float*)d_in[5];
    float* out = (float*)d_out;

    float* P   = (float*)d_ws;                  // 2176 x 512 fp32 = 4.46 MB
    float* pw2 = P + (size_t)M_TOT * H_DIM;     // 16 x 2176 fp32 slices
    float* P2  = pw2 + (size_t)NTILE * M_TOT;   // 4 x 2048 x 128 fp32 = 4.2 MB

    proj_kernel  <<<dim3(68 * NTILE),                     256, 0, stream>>>(img, txt, W1, b1, W2, P, pw2);
    sim_kernel   <<<dim3(N_IMG / 64, K_TXT / 32, NSLAB),  256, 0, stream>>>(P, W2, P2);
    reduce_kernel<<<dim3(N_IMG / 8),                      256, 0, stream>>>(P2, pw2, b2, out);
}